// Round 18
// baseline (145.745 us; speedup 1.0000x reference)
//
#include <hip/hip_runtime.h>

typedef short short8 __attribute__((ext_vector_type(8)));
typedef float f32x4 __attribute__((ext_vector_type(4)));

#define AS1 __attribute__((address_space(1)))
#define AS3 __attribute__((address_space(3)))

__device__ __forceinline__ void gload16(const void* g, void* l) {
    __builtin_amdgcn_global_load_lds((const AS1 unsigned int*)g, (AS3 unsigned int*)l, 16, 0, 0);
}

__device__ __forceinline__ unsigned short f2bf(float f) {
    union { float f; unsigned u; } c; c.f = f;
    unsigned r = (c.u + 0x7FFFu + ((c.u >> 16) & 1u)) >> 16;
    return (unsigned short)r;
}

__device__ __forceinline__ unsigned cvtpk(float a, float b) {
    unsigned r;
    asm("v_cvt_pk_bf16_f32 %0, %1, %2" : "=v"(r) : "v"(a), "v"(b));
    return r;
}

__device__ __forceinline__ void mfma16(f32x4& d, short8 a, short8 b) {
    asm("v_mfma_f32_16x16x32_bf16 %0, %1, %2, %0" : "+v"(d) : "v"(a), "v"(b));
}

// q pre-scale: 1/sqrt(64) * log2(e) -> softmax via exp2
#define QSCALE 0.18033688011112042f
// fixed softmax reference (exp2 domain): |s| <~ 10 << 24, P = exp2(s-24) in
// [2^-34, 1]; O = sum(P*V)/sum(P) exact (2^(m-24) cancels).
#define SMREF 24.0f

// ---------------- fused fp32 -> bf16 convert ----------------
#define XN4 2097152
#define WIN4 786432
#define WOUT4 262144
__global__ __launch_bounds__(256) void cvt_all(const float* __restrict__ x,
                                               const float* __restrict__ w_in,
                                               const float* __restrict__ w_out,
                                               unsigned short* __restrict__ xb,
                                               unsigned short* __restrict__ winb,
                                               unsigned short* __restrict__ woutb) {
    int idx = blockIdx.x * 256 + threadIdx.x;
    int stride = gridDim.x * 256;
    for (int i = idx; i < XN4 + WIN4 + WOUT4; i += stride) {
        const float4* src;
        ushort4* dst;
        int j;
        if (i < XN4) {
            src = (const float4*)x; dst = (ushort4*)xb; j = i;
        } else if (i < XN4 + WIN4) {
            src = (const float4*)w_in; dst = (ushort4*)winb; j = i - XN4;
        } else {
            src = (const float4*)w_out; dst = (ushort4*)woutb; j = i - XN4 - WIN4;
        }
        float4 v = src[j];
        ushort4 o;
        o.x = f2bf(v.x); o.y = f2bf(v.y); o.z = f2bf(v.z); o.w = f2bf(v.w);
        dst[j] = o;
    }
}

// ---------------- QKV GEMM: 128x256 tile, 512 thr = 8 waves (2M x 4N), 64x64/wave ----------------
// Same proven 64x64 wave tile & swizzle; LDS As[128][64]+Bs[256][64] = 48 KB ->
// 3 blocks/CU x 8 waves = up to 24 waves/CU (occupancy GAIN, unlike r10-r15
// variants); staged bytes -23% (B amortized over 256 cols); barriers/output halved.
// grid (64 m, 12 n): bid%8 = m%8 -> A-panel sharers stay on one XCD.
__global__ __launch_bounds__(512) void gemm_qkv(
    const unsigned short* __restrict__ A, const unsigned short* __restrict__ B,
    const float* __restrict__ bias, int K,
    unsigned short* __restrict__ qb, unsigned short* __restrict__ kb,
    unsigned short* __restrict__ vtb) {
    __shared__ unsigned short As[128 * 64];
    __shared__ unsigned short Bs[256 * 64];
    const int tid = threadIdx.x;
    const int lane = tid & 63;
    const int wv = tid >> 6;                 // 0..7
    const int wm = (wv >> 2) * 64;           // 2 M positions
    const int wn = (wv & 3) * 64;            // 4 N positions
    const int lr = lane & 15, lg = lane >> 4;
    const int x7 = lr & 7;
    const int m0 = blockIdx.x * 128, n0 = blockIdx.y * 256;

    f32x4 acc[4][4];
#pragma unroll
    for (int i = 0; i < 4; i++)
#pragma unroll
        for (int j = 0; j < 4; j++) acc[i][j] = (f32x4){0.f, 0.f, 0.f, 0.f};

    // staging: sr = tid>>3 (0..63), chunk = tid&7; row = j*64 + sr (row&7 = sr&7).
    const int sr = tid >> 3;
    const int sc = ((tid & 7) ^ ((tid >> 3) & 7)) * 8;
    const unsigned short* Ag = A + (size_t)(m0 + sr) * K + sc;
    const unsigned short* Bg = B + (size_t)(n0 + sr) * K + sc;

    for (int kt = 0; kt < K; kt += 64) {
        __syncthreads();
#pragma unroll
        for (int j = 0; j < 2; j++)
            gload16(Ag + (size_t)(j * 64) * K + kt, As + j * 4096 + tid * 8);
#pragma unroll
        for (int j = 0; j < 4; j++)
            gload16(Bg + (size_t)(j * 64) * K + kt, Bs + j * 4096 + tid * 8);
        __syncthreads();
#pragma unroll
        for (int ks = 0; ks < 2; ks++) {
            const int co = ((ks * 4 + lg) ^ x7) * 8;
            short8 af[4], bf[4];
#pragma unroll
            for (int mi = 0; mi < 4; mi++)
                af[mi] = *(const short8*)(As + (wm + mi * 16 + lr) * 64 + co);
#pragma unroll
            for (int ni = 0; ni < 4; ni++)
                bf[ni] = *(const short8*)(Bs + (wn + ni * 16 + lr) * 64 + co);
#pragma unroll
            for (int mi = 0; mi < 4; mi++)
#pragma unroll
                for (int ni = 0; ni < 4; ni++) mfma16(acc[mi][ni], af[mi], bf[ni]);
        }
    }

    // ---------------- QKV scatter epilogue (proven logic) ----------------
#pragma unroll
    for (int ni = 0; ni < 4; ni++) {
        const int col = n0 + wn + ni * 16 + lr;
        const float bia = bias[col];
        const unsigned h = (unsigned)col / 192u;
        const int rem = col - (int)h * 192;
        const int tq = rem >> 6, d = rem & 63;
#pragma unroll
        for (int mi = 0; mi < 4; mi++) {
            const int row = m0 + wm + mi * 16 + lg * 4;
            const int bb = row >> 10, s = row & 1023;
            const int bh = bb * 16 + (int)h;
            if (tq == 0) {
#pragma unroll
                for (int r = 0; r < 4; r++)
                    qb[((size_t)bh * 1024 + s + r) * 64 + d] =
                        f2bf((acc[mi][ni][r] + bia) * QSCALE);
            } else if (tq == 1) {
#pragma unroll
                for (int r = 0; r < 4; r++)
                    kb[((size_t)bh * 1024 + s + r) * 64 + d] = f2bf(acc[mi][ni][r] + bia);
            } else {
                uint2 pk;
                pk.x = cvtpk(acc[mi][ni][0] + bia, acc[mi][ni][1] + bia);
                pk.y = cvtpk(acc[mi][ni][2] + bia, acc[mi][ni][3] + bia);
                *(uint2*)(vtb + ((size_t)bh * 64 + d) * 1024 + s) = pk;
            }
        }
    }
}

// ---------------- proj GEMM (round-16 proven 128x128 single-buffer, fp32 out) ----------------
__global__ __launch_bounds__(256) void gemm_proj(
    const unsigned short* __restrict__ A, const unsigned short* __restrict__ B,
    const float* __restrict__ bias, int K, int N, float* __restrict__ Cf) {
    __shared__ unsigned short As[128 * 64];
    __shared__ unsigned short Bs[128 * 64];
    const int tid = threadIdx.x;
    const int lane = tid & 63;
    const int wv = tid >> 6;
    const int wm = (wv >> 1) * 64, wn = (wv & 1) * 64;
    const int lr = lane & 15, lg = lane >> 4;
    const int x7 = lr & 7;
    const int m0 = blockIdx.x * 128, n0 = blockIdx.y * 128;

    f32x4 acc[4][4];
#pragma unroll
    for (int i = 0; i < 4; i++)
#pragma unroll
        for (int j = 0; j < 4; j++) acc[i][j] = (f32x4){0.f, 0.f, 0.f, 0.f};

    const int sr = tid >> 3;
    const int sc = ((tid & 7) ^ ((tid >> 3) & 7)) * 8;
    const unsigned short* Ag = A + (size_t)(m0 + sr) * K + sc;
    const unsigned short* Bg = B + (size_t)(n0 + sr) * K + sc;
    unsigned short* Asl = As + tid * 8;
    unsigned short* Bsl = Bs + tid * 8;

    for (int kt = 0; kt < K; kt += 64) {
        __syncthreads();
#pragma unroll
        for (int i = 0; i < 4; i++) {
            gload16(Ag + (size_t)(i * 32) * K + kt, Asl + i * 2048);
            gload16(Bg + (size_t)(i * 32) * K + kt, Bsl + i * 2048);
        }
        __syncthreads();
#pragma unroll
        for (int ks = 0; ks < 2; ks++) {
            short8 af[4], bf[4];
#pragma unroll
            for (int mi = 0; mi < 4; mi++)
                af[mi] = *(const short8*)(As + (wm + mi * 16 + lr) * 64 +
                                          (((ks * 4 + lg) ^ x7) * 8));
#pragma unroll
            for (int ni = 0; ni < 4; ni++)
                bf[ni] = *(const short8*)(Bs + (wn + ni * 16 + lr) * 64 +
                                          (((ks * 4 + lg) ^ x7) * 8));
#pragma unroll
            for (int mi = 0; mi < 4; mi++)
#pragma unroll
                for (int ni = 0; ni < 4; ni++) mfma16(acc[mi][ni], af[mi], bf[ni]);
        }
    }

#pragma unroll
    for (int ni = 0; ni < 4; ni++) {
        const int col = n0 + wn + ni * 16 + lr;
        const float bia = bias[col];
#pragma unroll
        for (int mi = 0; mi < 4; mi++) {
            const int row = m0 + wm + mi * 16 + lg * 4;
#pragma unroll
            for (int r = 0; r < 4; r++)
                Cf[(size_t)(row + r) * N + col] = acc[mi][ni][r] + bia;
        }
    }
}

// ---------------- flash attention (round-17 proven: 512 thr / 256 q per block) ----------------
__device__ __forceinline__ void softmax_half(f32x4 (&s)[4], float& lpart,
                                             unsigned short* pbuf,
                                             int lr, int lg, int x7) {
    float p[4][4];
#pragma unroll
    for (int kt = 0; kt < 4; kt++)
#pragma unroll
        for (int r = 0; r < 4; r++) {
            p[kt][r] = __builtin_amdgcn_exp2f(s[kt][r] - SMREF);
            lpart += p[kt][r];
        }
#pragma unroll
    for (int kt = 0; kt < 4; kt++)
#pragma unroll
        for (int w2 = 0; w2 < 2; w2++) {
            const unsigned pk = cvtpk(p[kt][2 * w2], p[kt][2 * w2 + 1]);
            const int col = (kt * 16 + lg * 4 + 2 * w2) ^ (x7 << 3);
            *(unsigned*)(pbuf + lr * 64 + col) = pk;
        }
}

__global__ __launch_bounds__(512) void attn_fwd(
    const unsigned short* __restrict__ qg, const unsigned short* __restrict__ kg,
    const unsigned short* __restrict__ vtg, unsigned short* __restrict__ vals) {
    __shared__ unsigned short Ks[2][64 * 64];
    __shared__ unsigned short Vts[2][64 * 64];
    __shared__ unsigned short Ps[8 * 2048];
    const int tid = threadIdx.x, lane = tid & 63, w = tid >> 6;
    const int lr = lane & 15, lg = lane >> 4;
    const int x7 = lr & 7;
    const int bh = blockIdx.x;
    const int q0 = blockIdx.y * 256 + w * 32;

    const unsigned short* qrowA = qg + ((size_t)bh * 1024 + q0 + lr) * 64;
    const unsigned short* qrowB = qrowA + 16 * 64;
    short8 qA[2], qB[2];
    qA[0] = *(const short8*)(qrowA + lg * 8);
    qA[1] = *(const short8*)(qrowA + 32 + lg * 8);
    qB[0] = *(const short8*)(qrowB + lg * 8);
    qB[1] = *(const short8*)(qrowB + 32 + lg * 8);

    f32x4 oA[4], oB[4];
    float lA = 0.f, lB = 0.f;
#pragma unroll
    for (int i = 0; i < 4; i++) {
        oA[i] = (f32x4){0.f, 0.f, 0.f, 0.f};
        oB[i] = (f32x4){0.f, 0.f, 0.f, 0.f};
    }

    const unsigned short* kb = kg + (size_t)bh * 65536;
    const unsigned short* vb = vtg + (size_t)bh * 65536;
    unsigned short* pwl = Ps + w * 2048;

    const int srow = tid >> 3;
    const int scol = ((tid & 7) ^ (srow & 7)) * 8;

    auto stage = [&](int kv0, int buf) {
        gload16(kb + (size_t)(kv0 + srow) * 64 + scol, &Ks[buf][tid * 8]);
        gload16(vb + (size_t)srow * 1024 + kv0 + scol, &Vts[buf][tid * 8]);
    };

    stage(0, 0);
    __syncthreads();

    for (int t = 0; t < 16; ++t) {
        const int buf = t & 1;
        if (t < 15) stage((t + 1) * 64, buf ^ 1);
        const unsigned short* Kb = Ks[buf];
        const unsigned short* Vb = Vts[buf];

        f32x4 sA[4], sB[4];
#pragma unroll
        for (int i = 0; i < 4; i++) {
            sA[i] = (f32x4){0.f, 0.f, 0.f, 0.f};
            sB[i] = (f32x4){0.f, 0.f, 0.f, 0.f};
        }
#pragma unroll
        for (int kt = 0; kt < 4; kt++) {
            const short8 k0 = *(const short8*)(Kb + (kt * 16 + lr) * 64 + ((0 + lg) ^ x7) * 8);
            const short8 k1 = *(const short8*)(Kb + (kt * 16 + lr) * 64 + ((4 + lg) ^ x7) * 8);
            __builtin_amdgcn_s_setprio(1);
            mfma16(sA[kt], k0, qA[0]);
            mfma16(sB[kt], k0, qB[0]);
            mfma16(sA[kt], k1, qA[1]);
            mfma16(sB[kt], k1, qB[1]);
            __builtin_amdgcn_s_setprio(0);
        }

        softmax_half(sA, lA, pwl, lr, lg, x7);
        softmax_half(sB, lB, pwl + 1024, lr, lg, x7);

        short8 pA[2], pB[2];
#pragma unroll
        for (int ks2 = 0; ks2 < 2; ks2++) {
            pA[ks2] = *(const short8*)(pwl + lr * 64 + (((ks2 * 4 + lg) ^ x7) * 8));
            pB[ks2] = *(const short8*)(pwl + 1024 + lr * 64 + (((ks2 * 4 + lg) ^ x7) * 8));
        }
#pragma unroll
        for (int mi = 0; mi < 4; mi++) {
            const short8 v0 = *(const short8*)(Vb + (mi * 16 + lr) * 64 + ((0 + lg) ^ x7) * 8);
            const short8 v1 = *(const short8*)(Vb + (mi * 16 + lr) * 64 + ((4 + lg) ^ x7) * 8);
            __builtin_amdgcn_s_setprio(1);
            mfma16(oA[mi], v0, pA[0]);
            mfma16(oB[mi], v0, pB[0]);
            mfma16(oA[mi], v1, pA[1]);
            mfma16(oB[mi], v1, pB[1]);
            __builtin_amdgcn_s_setprio(0);
        }

        __syncthreads();
    }

    lA += __shfl_xor(lA, 16); lA += __shfl_xor(lA, 32);
    lB += __shfl_xor(lB, 16); lB += __shfl_xor(lB, 32);

    const int bb = bh >> 4, hh = bh & 15;
    {
        const float inv = 1.f / lA;
        unsigned short* vp = vals + (size_t)(bb * 1024 + q0 + lr) * 1024 + hh * 64 + lg * 4;
#pragma unroll
        for (int mi = 0; mi < 4; mi++) {
            uint2 st;
            st.x = cvtpk(oA[mi][0] * inv, oA[mi][1] * inv);
            st.y = cvtpk(oA[mi][2] * inv, oA[mi][3] * inv);
            *(uint2*)(vp + mi * 16) = st;
        }
    }
    {
        const float inv = 1.f / lB;
        unsigned short* vp = vals + (size_t)(bb * 1024 + q0 + 16 + lr) * 1024 + hh * 64 + lg * 4;
#pragma unroll
        for (int mi = 0; mi < 4; mi++) {
            uint2 st;
            st.x = cvtpk(oB[mi][0] * inv, oB[mi][1] * inv);
            st.y = cvtpk(oB[mi][2] * inv, oB[mi][3] * inv);
            *(uint2*)(vp + mi * 16) = st;
        }
    }
}

extern "C" void kernel_launch(void* const* d_in, const int* in_sizes, int n_in,
                              void* d_out, int out_size, void* d_ws, size_t ws_size,
                              hipStream_t stream) {
    const float* x = (const float*)d_in[0];
    const float* w_in = (const float*)d_in[1];
    const float* b_in = (const float*)d_in[2];
    const float* w_out = (const float*)d_in[3];
    const float* b_out = (const float*)d_in[4];
    float* out = (float*)d_out;

    unsigned short* ws = (unsigned short*)d_ws;
    unsigned short* xb = ws;                   // 8388608  (reused as vals)
    unsigned short* winb = xb + 8388608;       // 3145728
    unsigned short* woutb = winb + 3145728;    // 1048576
    unsigned short* qb = woutb + 1048576;      // 8388608  (Q [bh,1024,64], pre-scaled)
    unsigned short* kb = qb + 8388608;         // 8388608
    unsigned short* vtb = kb + 8388608;        // 8388608  (V^T [bh,64,1024])
    unsigned short* vals = xb;                 // alias

    cvt_all<<<2048, 256, 0, stream>>>(x, w_in, w_out, xb, winb, woutb);

    gemm_qkv<<<dim3(64, 12), 512, 0, stream>>>(xb, winb, b_in, 1024, qb, kb, vtb);
    attn_fwd<<<dim3(128, 4), 512, 0, stream>>>(qb, kb, vtb, vals);
    gemm_proj<<<dim3(64, 8), 256, 0, stream>>>(vals, woutb, b_out, 1024, 1024, out);
}

// Round 19
// 137.520 us; speedup vs baseline: 1.0598x; 1.0598x over previous
//
#include <hip/hip_runtime.h>

typedef short short8 __attribute__((ext_vector_type(8)));
typedef float f32x4 __attribute__((ext_vector_type(4)));

#define AS1 __attribute__((address_space(1)))
#define AS3 __attribute__((address_space(3)))

__device__ __forceinline__ void gload16(const void* g, void* l) {
    __builtin_amdgcn_global_load_lds((const AS1 unsigned int*)g, (AS3 unsigned int*)l, 16, 0, 0);
}

__device__ __forceinline__ unsigned short f2bf(float f) {
    union { float f; unsigned u; } c; c.f = f;
    unsigned r = (c.u + 0x7FFFu + ((c.u >> 16) & 1u)) >> 16;
    return (unsigned short)r;
}

__device__ __forceinline__ unsigned cvtpk(float a, float b) {
    unsigned r;
    asm("v_cvt_pk_bf16_f32 %0, %1, %2" : "=v"(r) : "v"(a), "v"(b));
    return r;
}

__device__ __forceinline__ void mfma16(f32x4& d, short8 a, short8 b) {
    asm("v_mfma_f32_16x16x32_bf16 %0, %1, %2, %0" : "+v"(d) : "v"(a), "v"(b));
}

// q pre-scale: 1/sqrt(64) * log2(e) -> softmax via exp2
#define QSCALE 0.18033688011112042f
// fixed softmax reference (exp2 domain): |s| <~ 10 << 24, P = exp2(s-24) in
// [2^-34, 1]; O = sum(P*V)/sum(P) exact (2^(m-24) cancels).
#define SMREF 24.0f

// ---------------- fused fp32 -> bf16 convert ----------------
#define XN4 2097152
#define WIN4 786432
#define WOUT4 262144
__global__ __launch_bounds__(256) void cvt_all(const float* __restrict__ x,
                                               const float* __restrict__ w_in,
                                               const float* __restrict__ w_out,
                                               unsigned short* __restrict__ xb,
                                               unsigned short* __restrict__ winb,
                                               unsigned short* __restrict__ woutb) {
    int idx = blockIdx.x * 256 + threadIdx.x;
    int stride = gridDim.x * 256;
    for (int i = idx; i < XN4 + WIN4 + WOUT4; i += stride) {
        const float4* src;
        ushort4* dst;
        int j;
        if (i < XN4) {
            src = (const float4*)x; dst = (ushort4*)xb; j = i;
        } else if (i < XN4 + WIN4) {
            src = (const float4*)w_in; dst = (ushort4*)winb; j = i - XN4;
        } else {
            src = (const float4*)w_out; dst = (ushort4*)woutb; j = i - XN4 - WIN4;
        }
        float4 v = src[j];
        ushort4 o;
        o.x = f2bf(v.x); o.y = f2bf(v.y); o.z = f2bf(v.z); o.w = f2bf(v.w);
        dst[j] = o;
    }
}

// ---------------- 128x128 NT GEMM (session optimum: single-buffer + swizzle, no setprio) ----------------
// 8-variant bracket (r2..r18): this simple 2-barrier 256-thread structure wins
// every A/B. 32 KB LDS -> ~2.4 resident blocks/CU; TLP across blocks hides
// staging latency better than any pipeline that spends LDS/VGPR/block-width.
template <int EPI>
__global__ __launch_bounds__(256) void gemm_nt(
    const unsigned short* __restrict__ A, const unsigned short* __restrict__ B,
    const float* __restrict__ bias, int M, int N, int K,
    float* __restrict__ Cf, unsigned short* __restrict__ qb,
    unsigned short* __restrict__ kb, unsigned short* __restrict__ vtb) {
    __shared__ unsigned short As[128 * 64];
    __shared__ unsigned short Bs[128 * 64];
    const int tid = threadIdx.x;
    const int lane = tid & 63;
    const int wv = tid >> 6;
    const int wm = (wv >> 1) * 64, wn = (wv & 1) * 64;
    const int lr = lane & 15, lg = lane >> 4;
    const int x7 = lr & 7;
    const int m0 = blockIdx.x * 128, n0 = blockIdx.y * 128;

    f32x4 acc[4][4];
#pragma unroll
    for (int i = 0; i < 4; i++)
#pragma unroll
        for (int j = 0; j < 4; j++) acc[i][j] = (f32x4){0.f, 0.f, 0.f, 0.f};

    const int sr = tid >> 3;
    const int sc = ((tid & 7) ^ ((tid >> 3) & 7)) * 8;
    const unsigned short* Ag = A + (size_t)(m0 + sr) * K + sc;
    const unsigned short* Bg = B + (size_t)(n0 + sr) * K + sc;
    unsigned short* Asl = As + tid * 8;
    unsigned short* Bsl = Bs + tid * 8;

    for (int kt = 0; kt < K; kt += 64) {
        __syncthreads();
#pragma unroll
        for (int i = 0; i < 4; i++) {
            gload16(Ag + (size_t)(i * 32) * K + kt, Asl + i * 2048);
            gload16(Bg + (size_t)(i * 32) * K + kt, Bsl + i * 2048);
        }
        __syncthreads();
#pragma unroll
        for (int ks = 0; ks < 2; ks++) {
            short8 af[4], bf[4];
#pragma unroll
            for (int mi = 0; mi < 4; mi++)
                af[mi] = *(const short8*)(As + (wm + mi * 16 + lr) * 64 +
                                          (((ks * 4 + lg) ^ x7) * 8));
#pragma unroll
            for (int ni = 0; ni < 4; ni++)
                bf[ni] = *(const short8*)(Bs + (wn + ni * 16 + lr) * 64 +
                                          (((ks * 4 + lg) ^ x7) * 8));
#pragma unroll
            for (int mi = 0; mi < 4; mi++)
#pragma unroll
                for (int ni = 0; ni < 4; ni++) mfma16(acc[mi][ni], af[mi], bf[ni]);
        }
    }

    // ---------------- epilogue ----------------
#pragma unroll
    for (int ni = 0; ni < 4; ni++) {
        const int col = n0 + wn + ni * 16 + lr;
        const float bia = bias[col];
        const unsigned h = (unsigned)col / 192u;
        const int rem = col - (int)h * 192;
        const int tq = rem >> 6, d = rem & 63;
#pragma unroll
        for (int mi = 0; mi < 4; mi++) {
            const int row = m0 + wm + mi * 16 + lg * 4;
            if (EPI == 1) {
#pragma unroll
                for (int r = 0; r < 4; r++)
                    Cf[(size_t)(row + r) * N + col] = acc[mi][ni][r] + bia;
            } else {
                const int bb = row >> 10, s = row & 1023;
                const int bh = bb * 16 + (int)h;
                if (tq == 0) {
#pragma unroll
                    for (int r = 0; r < 4; r++)
                        qb[((size_t)bh * 1024 + s + r) * 64 + d] =
                            f2bf((acc[mi][ni][r] + bia) * QSCALE);
                } else if (tq == 1) {
#pragma unroll
                    for (int r = 0; r < 4; r++)
                        kb[((size_t)bh * 1024 + s + r) * 64 + d] = f2bf(acc[mi][ni][r] + bia);
                } else {
                    uint2 pk;
                    pk.x = cvtpk(acc[mi][ni][0] + bia, acc[mi][ni][1] + bia);
                    pk.y = cvtpk(acc[mi][ni][2] + bia, acc[mi][ni][3] + bia);
                    *(uint2*)(vtb + ((size_t)bh * 64 + d) * 1024 + s) = pk;
                }
            }
        }
    }
}

// ---------------- flash attention (round-17 proven: 512 thr / 256 q per block) ----------------
__device__ __forceinline__ void softmax_half(f32x4 (&s)[4], float& lpart,
                                             unsigned short* pbuf,
                                             int lr, int lg, int x7) {
    float p[4][4];
#pragma unroll
    for (int kt = 0; kt < 4; kt++)
#pragma unroll
        for (int r = 0; r < 4; r++) {
            p[kt][r] = __builtin_amdgcn_exp2f(s[kt][r] - SMREF);
            lpart += p[kt][r];
        }
#pragma unroll
    for (int kt = 0; kt < 4; kt++)
#pragma unroll
        for (int w2 = 0; w2 < 2; w2++) {
            const unsigned pk = cvtpk(p[kt][2 * w2], p[kt][2 * w2 + 1]);
            const int col = (kt * 16 + lg * 4 + 2 * w2) ^ (x7 << 3);
            *(unsigned*)(pbuf + lr * 64 + col) = pk;
        }
}

__global__ __launch_bounds__(512) void attn_fwd(
    const unsigned short* __restrict__ qg, const unsigned short* __restrict__ kg,
    const unsigned short* __restrict__ vtg, unsigned short* __restrict__ vals) {
    __shared__ unsigned short Ks[2][64 * 64];
    __shared__ unsigned short Vts[2][64 * 64];
    __shared__ unsigned short Ps[8 * 2048];
    const int tid = threadIdx.x, lane = tid & 63, w = tid >> 6;  // w = 0..7
    const int lr = lane & 15, lg = lane >> 4;
    const int x7 = lr & 7;
    // grid = (128 bh, 4 qblk): bid%8 = bh%8 -> all q-blocks of a bh on one XCD.
    const int bh = blockIdx.x;
    const int q0 = blockIdx.y * 256 + w * 32;

    const unsigned short* qrowA = qg + ((size_t)bh * 1024 + q0 + lr) * 64;
    const unsigned short* qrowB = qrowA + 16 * 64;
    short8 qA[2], qB[2];
    qA[0] = *(const short8*)(qrowA + lg * 8);
    qA[1] = *(const short8*)(qrowA + 32 + lg * 8);
    qB[0] = *(const short8*)(qrowB + lg * 8);
    qB[1] = *(const short8*)(qrowB + 32 + lg * 8);

    f32x4 oA[4], oB[4];
    float lA = 0.f, lB = 0.f;
#pragma unroll
    for (int i = 0; i < 4; i++) {
        oA[i] = (f32x4){0.f, 0.f, 0.f, 0.f};
        oB[i] = (f32x4){0.f, 0.f, 0.f, 0.f};
    }

    const unsigned short* kb = kg + (size_t)bh * 65536;
    const unsigned short* vb = vtg + (size_t)bh * 65536;
    unsigned short* pwl = Ps + w * 2048;

    const int srow = tid >> 3;                        // 0..63 (512 thr -> 1 row each)
    const int scol = ((tid & 7) ^ (srow & 7)) * 8;    // pre-swizzled source chunk

    auto stage = [&](int kv0, int buf) {
        gload16(kb + (size_t)(kv0 + srow) * 64 + scol, &Ks[buf][tid * 8]);
        gload16(vb + (size_t)srow * 1024 + kv0 + scol, &Vts[buf][tid * 8]);
    };

    stage(0, 0);
    __syncthreads();

    for (int t = 0; t < 16; ++t) {
        const int buf = t & 1;
        if (t < 15) stage((t + 1) * 64, buf ^ 1);
        const unsigned short* Kb = Ks[buf];
        const unsigned short* Vb = Vts[buf];

        f32x4 sA[4], sB[4];
#pragma unroll
        for (int i = 0; i < 4; i++) {
            sA[i] = (f32x4){0.f, 0.f, 0.f, 0.f};
            sB[i] = (f32x4){0.f, 0.f, 0.f, 0.f};
        }
#pragma unroll
        for (int kt = 0; kt < 4; kt++) {
            const short8 k0 = *(const short8*)(Kb + (kt * 16 + lr) * 64 + ((0 + lg) ^ x7) * 8);
            const short8 k1 = *(const short8*)(Kb + (kt * 16 + lr) * 64 + ((4 + lg) ^ x7) * 8);
            __builtin_amdgcn_s_setprio(1);
            mfma16(sA[kt], k0, qA[0]);
            mfma16(sB[kt], k0, qB[0]);
            mfma16(sA[kt], k1, qA[1]);
            mfma16(sB[kt], k1, qB[1]);
            __builtin_amdgcn_s_setprio(0);
        }

        softmax_half(sA, lA, pwl, lr, lg, x7);
        softmax_half(sB, lB, pwl + 1024, lr, lg, x7);

        short8 pA[2], pB[2];
#pragma unroll
        for (int ks2 = 0; ks2 < 2; ks2++) {
            pA[ks2] = *(const short8*)(pwl + lr * 64 + (((ks2 * 4 + lg) ^ x7) * 8));
            pB[ks2] = *(const short8*)(pwl + 1024 + lr * 64 + (((ks2 * 4 + lg) ^ x7) * 8));
        }
#pragma unroll
        for (int mi = 0; mi < 4; mi++) {
            const short8 v0 = *(const short8*)(Vb + (mi * 16 + lr) * 64 + ((0 + lg) ^ x7) * 8);
            const short8 v1 = *(const short8*)(Vb + (mi * 16 + lr) * 64 + ((4 + lg) ^ x7) * 8);
            __builtin_amdgcn_s_setprio(1);
            mfma16(oA[mi], v0, pA[0]);
            mfma16(oB[mi], v0, pB[0]);
            mfma16(oA[mi], v1, pA[1]);
            mfma16(oB[mi], v1, pB[1]);
            __builtin_amdgcn_s_setprio(0);
        }

        __syncthreads();
    }

    lA += __shfl_xor(lA, 16); lA += __shfl_xor(lA, 32);
    lB += __shfl_xor(lB, 16); lB += __shfl_xor(lB, 32);

    const int bb = bh >> 4, hh = bh & 15;
    {
        const float inv = 1.f / lA;
        unsigned short* vp = vals + (size_t)(bb * 1024 + q0 + lr) * 1024 + hh * 64 + lg * 4;
#pragma unroll
        for (int mi = 0; mi < 4; mi++) {
            uint2 st;
            st.x = cvtpk(oA[mi][0] * inv, oA[mi][1] * inv);
            st.y = cvtpk(oA[mi][2] * inv, oA[mi][3] * inv);
            *(uint2*)(vp + mi * 16) = st;
        }
    }
    {
        const float inv = 1.f / lB;
        unsigned short* vp = vals + (size_t)(bb * 1024 + q0 + 16 + lr) * 1024 + hh * 64 + lg * 4;
#pragma unroll
        for (int mi = 0; mi < 4; mi++) {
            uint2 st;
            st.x = cvtpk(oB[mi][0] * inv, oB[mi][1] * inv);
            st.y = cvtpk(oB[mi][2] * inv, oB[mi][3] * inv);
            *(uint2*)(vp + mi * 16) = st;
        }
    }
}

extern "C" void kernel_launch(void* const* d_in, const int* in_sizes, int n_in,
                              void* d_out, int out_size, void* d_ws, size_t ws_size,
                              hipStream_t stream) {
    const float* x = (const float*)d_in[0];
    const float* w_in = (const float*)d_in[1];
    const float* b_in = (const float*)d_in[2];
    const float* w_out = (const float*)d_in[3];
    const float* b_out = (const float*)d_in[4];
    float* out = (float*)d_out;

    unsigned short* ws = (unsigned short*)d_ws;
    unsigned short* xb = ws;                   // 8388608  (reused as vals)
    unsigned short* winb = xb + 8388608;       // 3145728
    unsigned short* woutb = winb + 3145728;    // 1048576
    unsigned short* qb = woutb + 1048576;      // 8388608  (Q [bh,1024,64], pre-scaled)
    unsigned short* kb = qb + 8388608;         // 8388608
    unsigned short* vtb = kb + 8388608;        // 8388608  (V^T [bh,64,1024])
    unsigned short* vals = xb;                 // alias

    cvt_all<<<2048, 256, 0, stream>>>(x, w_in, w_out, xb, winb, woutb);

    gemm_nt<0><<<dim3(64, 24), 256, 0, stream>>>(xb, winb, b_in, 8192, 3072, 1024,
                                                 nullptr, qb, kb, vtb);
    attn_fwd<<<dim3(128, 4), 512, 0, stream>>>(qb, kb, vtb, vals);
    gemm_nt<1><<<dim3(64, 8), 256, 0, stream>>>(vals, woutb, b_out, 8192, 1024, 1024,
                                                out, nullptr, nullptr, nullptr);
}